// Round 2
// baseline (341.852 us; speedup 1.0000x reference)
//
#include <hip/hip_runtime.h>
#include <math.h>

#define IMG 512
#define PLANES 96            // 32 N * 3 C
#define XS_W 54              // valid output columns per wave (64 lanes - 10 halo)
#define NXS 10               // ceil(512/54)
#define YS_H 64              // output rows per wave
#define NYS 8                // 512/64
#define WPB 4                // waves per block
#define NSLOT 32
#define ACC_STRIDE 16        // doubles per atomic slot (128 B cacheline pad)
#define INV_NPIX (1.0 / 25165824.0)

typedef float f32x2 __attribute__((ext_vector_type(2)));

// ws layout: [0, 4096) : double acc[NSLOT*ACC_STRIDE]; [4096, 4140) : float gw[11]

__global__ void ssim_init(double* __restrict__ acc, float* __restrict__ gwp,
                          const float* __restrict__ win) {
    int i = threadIdx.x;
    if (i < NSLOT * ACC_STRIDE) acc[i] = 0.0;
    // separable 1-D Gaussian from diagonal of 2-D window: w2d[i][i]=g[i]^2
    if (i < 11) gwp[i] = sqrtf(win[i * 12]);
}

// ---- packed-FP32: 2 rows per lane; LLVM selects v_pk_{fma,mul,add}_f32 on
//      gfx950 (HasPackedFP32Ops) from <2 x float> ops. No inline asm. ----
static __device__ __forceinline__ f32x2 pk_fma(f32x2 a, f32x2 b, f32x2 c) {
    return __builtin_elementwise_fma(a, b, c);
}
static __device__ __forceinline__ f32x2 splat_lo(f32x2 v) { f32x2 r; r.x = v.x; r.y = v.x; return r; }
static __device__ __forceinline__ f32x2 splat_hi(f32x2 v) { f32x2 r; r.x = v.y; r.y = v.y; return r; }

static __device__ __forceinline__ f32x2 bperm_pair(int idx, f32x2 v) {
    f32x2 r;
    r.x = __int_as_float(__builtin_amdgcn_ds_bpermute(idx, __float_as_int(v.x)));
    r.y = __int_as_float(__builtin_amdgcn_ds_bpermute(idx, __float_as_int(v.y)));
    return r;
}

static __device__ __forceinline__ void emit_row(
    float mu1s, float mu2s, float mu12, float x11, float x22, float x12,
    bool ok, float& sL, float& sC, float& sS)
{
    float v1 = x11 - mu1s, v2 = x22 - mu2s, v12 = x12 - mu12;
    float a1 = fabsf(v1), a2 = fabsf(v2);
    float q12 = sqrtf(a1 * a2);                 // sqrt(a1)*sqrt(a2)
    const float C1 = 1e-4f, C2 = 9e-4f, C3 = 4.5e-4f;
    float eL = __fdividef(2.f * mu12 + C1, mu1s + mu2s + C1);
    float eC = __fdividef(2.f * q12 + C2, a1 + a2 + C2);
    float eS = __fdividef(v12 + C3, q12 + C3);
    if (ok) { sL += eL; sC += eC; sS += eS; }
}

// One step processes input rows t=2u (lo) and t=2u+1 (hi) as a packed pair.
// Ring: 6 packed slots per stream; slot s holds output-row pair p == s (mod 6).
// Pair p accumulates at steps u=p..p+5 (tap distance d=2(u-p)), emits at u=p+5,
// slot zeroed unconditionally each step (kills phantom p<0 contributions —
// same invariant as the scalar 11-slot ring). Per-output-row tap order is
// increasing t', matching the scalar kernel; boundary taps have exact 0 weight.
template<int P>
__device__ __forceinline__ void pair_step(
    int u, int y0, bool col_ok,
    const float* __restrict__ p1, const float* __restrict__ p2,
    f32x2& x1p, f32x2& x2p, const int (&si)[11],
    const f32x2 (&g2h)[6], const f32x2 (&wA)[6], const f32x2 (&wB)[6],
    f32x2 (&A)[5][6], bool out_ok, float& sL, float& sC, float& sS)
{
    // ---- prefetch rows t = 2u+2, 2u+3 (coalesced: lane = column) ----
    const int gya = y0 - 3 + 2 * u;            // y0-5 + (2u+2)
    const int gyb = gya + 1;
    f32x2 nx1 = {0.f, 0.f}, nx2 = {0.f, 0.f};
    if (col_ok && (unsigned)gya < IMG) { int o = gya * IMG; nx1.x = p1[o]; nx2.x = p2[o]; }
    if (col_ok && (unsigned)gyb < IMG) { int o = gyb * IMG; nx1.y = p1[o]; nx2.y = p2[o]; }

    // ---- horizontal 11-tap for 5 quantities, both rows per instruction ----
    f32x2 H1 = {0.f,0.f}, H2 = {0.f,0.f}, H11 = {0.f,0.f}, H22 = {0.f,0.f}, H12 = {0.f,0.f};
    #pragma unroll
    for (int j = 0; j < 11; ++j) {
        const int hj = (j <= 5) ? j : 10 - j;  // g[j] == g[10-j] bitwise (symmetric)
        f32x2 aj, bj;
        if (j == 5) { aj = x1p; bj = x2p; }
        else        { aj = bperm_pair(si[j], x1p); bj = bperm_pair(si[j], x2p); }
        f32x2 t1 = g2h[hj] * aj;
        f32x2 t2 = g2h[hj] * bj;
        H1  = H1 + t1;
        H2  = H2 + t2;
        H11 = pk_fma(t1, aj, H11);
        H22 = pk_fma(t2, bj, H22);
        H12 = pk_fma(t1, bj, H12);
    }

    // ---- vertical accumulate: pair p=u-e in slot (P-e)%6, d=2e ----
    // row 2p   gets g[2e]*H_lo   (wA.x) then g[2e+1]*H_hi (wB.x)
    // row 2p+1 gets g[2e-1]*H_lo (wA.y) then g[2e]*H_hi   (wB.y)
    const f32x2 H1l = splat_lo(H1),  H1h = splat_hi(H1);
    const f32x2 H2l = splat_lo(H2),  H2h = splat_hi(H2);
    const f32x2 Hal = splat_lo(H11), Hah = splat_hi(H11);
    const f32x2 Hbl = splat_lo(H22), Hbh = splat_hi(H22);
    const f32x2 Hcl = splat_lo(H12), Hch = splat_hi(H12);
    #pragma unroll
    for (int e = 0; e < 6; ++e) {
        const int s = (P - e + 6) % 6;
        A[0][s] = pk_fma(H1l, wA[e], A[0][s]);
        A[0][s] = pk_fma(H1h, wB[e], A[0][s]);
        A[1][s] = pk_fma(H2l, wA[e], A[1][s]);
        A[1][s] = pk_fma(H2h, wB[e], A[1][s]);
        A[2][s] = pk_fma(Hal, wA[e], A[2][s]);
        A[2][s] = pk_fma(Hah, wB[e], A[2][s]);
        A[3][s] = pk_fma(Hbl, wA[e], A[3][s]);
        A[3][s] = pk_fma(Hbh, wB[e], A[3][s]);
        A[4][s] = pk_fma(Hcl, wA[e], A[4][s]);
        A[4][s] = pk_fma(Hch, wB[e], A[4][s]);
    }

    // ---- emit completed pair p = u-5 (rows 2p, 2p+1), slot (P+1)%6 ----
    const int es = (P + 1) % 6;
    if (u >= 5) {                              // wave-uniform branch
        f32x2 mu1 = A[0][es], mu2 = A[1][es];
        f32x2 x11 = A[2][es], x22 = A[3][es], x12 = A[4][es];
        f32x2 mu1s = mu1 * mu1;
        f32x2 mu2s = mu2 * mu2;
        f32x2 mu12 = mu1 * mu2;
        emit_row(mu1s.x, mu2s.x, mu12.x, x11.x, x22.x, x12.x, out_ok, sL, sC, sS);
        emit_row(mu1s.y, mu2s.y, mu12.y, x11.y, x22.y, x12.y, out_ok, sL, sC, sS);
    }
    #pragma unroll
    for (int q = 0; q < 5; ++q) { A[q][es].x = 0.f; A[q][es].y = 0.f; }
    x1p = nx1; x2p = nx2;
}

__global__ __launch_bounds__(256, 3) void ssim_main(
    const float* __restrict__ img1, const float* __restrict__ img2,
    const float* __restrict__ gwp, double* __restrict__ acc)
{
    const int lane = threadIdx.x & 63;
    const int wid  = blockIdx.x * WPB + (threadIdx.x >> 6);
    const int plane = wid / (NXS * NYS);
    const int rem   = wid % (NXS * NYS);
    const int ys = rem / NXS, xs = rem % NXS;
    const int x0 = xs * XS_W;
    const int y0 = ys * YS_H;
    const int col = x0 - 5 + lane;
    const bool col_ok = (unsigned)col < IMG;
    const bool out_ok = (lane >= 5) && (lane <= 58) && col_ok;

    // bpermute byte-indices for lane shifts -5..+5 (loop-invariant)
    int si[11];
    #pragma unroll
    for (int j = 0; j < 11; ++j) si[j] = (lane + j - 5) << 2;

    // weights: uniform (kernel-arg pointer) loads -> SGPRs
    float gj[11];
    #pragma unroll
    for (int j = 0; j < 11; ++j) gj[j] = gwp[j];
    f32x2 g2h[6];                               // (g[j], g[j]) horizontal
    #pragma unroll
    for (int j = 0; j < 6; ++j) { g2h[j].x = gj[j]; g2h[j].y = gj[j]; }
    f32x2 wA[6], wB[6];                         // vertical pair weights, d=2e
    #pragma unroll
    for (int e = 0; e < 6; ++e) {
        wA[e].x = gj[2*e];
        wA[e].y = (e == 0) ? 0.f : gj[2*e - 1];
        wB[e].x = (e == 5) ? 0.f : gj[2*e + 1];
        wB[e].y = gj[2*e];
    }

    const float* p1 = img1 + (size_t)plane * (IMG * IMG) + col;
    const float* p2 = img2 + (size_t)plane * (IMG * IMG) + col;

    // load rows t=0,1 (gy = y0-5, y0-4)
    f32x2 x1p = {0.f, 0.f}, x2p = {0.f, 0.f};
    {
        int ga = y0 - 5, gb = y0 - 4;
        if (col_ok && (unsigned)ga < IMG) { int o = ga * IMG; x1p.x = p1[o]; x2p.x = p2[o]; }
        if (col_ok && (unsigned)gb < IMG) { int o = gb * IMG; x1p.y = p1[o]; x2p.y = p2[o]; }
    }

    f32x2 A[5][6];
    #pragma unroll
    for (int q = 0; q < 5; ++q)
        #pragma unroll
        for (int s = 0; s < 6; ++s) { A[q][s].x = 0.f; A[q][s].y = 0.f; }

    float sL = 0.f, sC = 0.f, sS = 0.f;

    #pragma unroll 1
    for (int U = 0; U < 36; U += 6) {          // u = 0..35 (t = 0..71)
        pair_step<0>(U+0, y0, col_ok, p1, p2, x1p, x2p, si, g2h, wA, wB, A, out_ok, sL, sC, sS);
        pair_step<1>(U+1, y0, col_ok, p1, p2, x1p, x2p, si, g2h, wA, wB, A, out_ok, sL, sC, sS);
        pair_step<2>(U+2, y0, col_ok, p1, p2, x1p, x2p, si, g2h, wA, wB, A, out_ok, sL, sC, sS);
        pair_step<3>(U+3, y0, col_ok, p1, p2, x1p, x2p, si, g2h, wA, wB, A, out_ok, sL, sC, sS);
        pair_step<4>(U+4, y0, col_ok, p1, p2, x1p, x2p, si, g2h, wA, wB, A, out_ok, sL, sC, sS);
        pair_step<5>(U+5, y0, col_ok, p1, p2, x1p, x2p, si, g2h, wA, wB, A, out_ok, sL, sC, sS);
    }
    // tail: u = 36 (t = 72,73), emits pair p=31 (rows 62,63)
    pair_step<0>(36, y0, col_ok, p1, p2, x1p, x2p, si, g2h, wA, wB, A, out_ok, sL, sC, sS);

    // ---- wave reduction (no barriers), then one diluted atomic set per wave ----
    #pragma unroll
    for (int off = 32; off > 0; off >>= 1) {
        sL += __shfl_down(sL, off, 64);
        sC += __shfl_down(sC, off, 64);
        sS += __shfl_down(sS, off, 64);
    }
    if (lane == 0) {
        double* slot = acc + (size_t)(wid & (NSLOT - 1)) * ACC_STRIDE;
        atomicAdd(slot + 0, (double)sL);
        atomicAdd(slot + 1, (double)sC);
        atomicAdd(slot + 2, (double)sS);
    }
}

__global__ void ssim_fin(const double* __restrict__ acc, float* __restrict__ out) {
    int i = threadIdx.x;
    if (i < 3) {
        double s = 0.0;
        for (int k = 0; k < NSLOT; ++k) s += acc[k * ACC_STRIDE + i];
        out[i] = (float)(s * INV_NPIX);
    }
}

extern "C" void kernel_launch(void* const* d_in, const int* in_sizes, int n_in,
                              void* d_out, int out_size, void* d_ws, size_t ws_size,
                              hipStream_t stream) {
    const float* img1 = (const float*)d_in[0];
    const float* img2 = (const float*)d_in[1];
    const float* win  = (const float*)d_in[2];
    float* out = (float*)d_out;
    double* acc = (double*)d_ws;
    float* gwp = (float*)((char*)d_ws + NSLOT * ACC_STRIDE * sizeof(double));

    ssim_init<<<1, 512, 0, stream>>>(acc, gwp, win);
    ssim_main<<<(PLANES * NXS * NYS) / WPB, 64 * WPB, 0, stream>>>(img1, img2, gwp, acc);
    ssim_fin<<<1, 64, 0, stream>>>(acc, out);
}

// Round 3
// 333.188 us; speedup vs baseline: 1.0260x; 1.0260x over previous
//
#include <hip/hip_runtime.h>
#include <math.h>

#define IMG 512
#define PLANES 96            // 32 N * 3 C
#define XS_W 54              // valid output columns per wave (64 lanes - 10 halo)
#define NXS 10               // ceil(512/54)
#define YS_H 64              // output rows per wave
#define NYS 8                // 512/64
#define WPB 4                // waves per block
#define NBLK ((PLANES * NXS * NYS) / WPB)   // 1920 blocks
#define INV_NPIX (1.0 / 25165824.0)

// ws layout: float4 part[NBLK]  (30720 B) — per-block partial sums, plain stores.

static __device__ __forceinline__ float rfl(float x) {
    return __int_as_float(__builtin_amdgcn_readfirstlane(__float_as_int(x)));
}

// One row step. Ring: 11 slots; at step t (phase P=t%11) the vertical loop
// writes each slot exactly once: slot (P+j+1)%11 gets tap weight g[10-j].
// j==10 targets slot P — the slot emitted at step t-1 — so it is OVERWRITTEN
// (mul) instead of zero+fma: exact same values, 5 fewer v_mov per step.
template<int P>
__device__ __forceinline__ void row_step(
    int T, int y0, bool col_ok,
    const float* __restrict__ p1, const float* __restrict__ p2,
    float& x1, float& x2, const int (&si)[11], const float (&g)[11],
    float (&A)[5][11], bool out_ok, float& sL, float& sC, float& sS)
{
    const int t = T + P;
    // ---- prefetch row t+1 (coalesced: lane = column) ----
    const int gy_next = y0 - 4 + t;
    float nx1 = 0.f, nx2 = 0.f;
    if (col_ok && (unsigned)gy_next < IMG) {
        int off = gy_next * IMG;
        nx1 = p1[off];
        nx2 = p2[off];
    }
    // ---- horizontal window via lane shifts (conflict-free bpermute) ----
    float a[11], b[11];
    #pragma unroll
    for (int j = 0; j < 11; ++j) {
        if (j == 5) { a[j] = x1; b[j] = x2; }
        else {
            a[j] = __int_as_float(__builtin_amdgcn_ds_bpermute(si[j], __float_as_int(x1)));
            b[j] = __int_as_float(__builtin_amdgcn_ds_bpermute(si[j], __float_as_int(x2)));
        }
    }
    // ---- horizontal 11-tap for 5 quantities (weights in SGPRs) ----
    float t1 = g[0] * a[0], t2 = g[0] * b[0];
    float H1 = t1, H2 = t2;
    float H11 = t1 * a[0], H22 = t2 * b[0], H12 = t1 * b[0];
    #pragma unroll
    for (int j = 1; j < 11; ++j) {
        float w = g[j];
        t1 = w * a[j]; t2 = w * b[j];
        H1 += t1; H2 += t2;
        H11 = fmaf(t1, a[j], H11);
        H22 = fmaf(t2, b[j], H22);
        H12 = fmaf(t1, b[j], H12);
    }
    // ---- vertical accumulate into ring: H_t -> output r=t-10+j, weight g[10-j],
    //      slot (P+j+1)%11 ; statically indexed since t ≡ P (mod 11) ----
    #pragma unroll
    for (int j = 0; j < 11; ++j) {
        const int s = (P + j + 1) % 11;
        float w = g[10 - j];
        if (j == 10) {                             // fresh slot (== P): overwrite
            A[0][s] = w * H1;
            A[1][s] = w * H2;
            A[2][s] = w * H11;
            A[3][s] = w * H22;
            A[4][s] = w * H12;
        } else {
            A[0][s] = fmaf(w, H1,  A[0][s]);
            A[1][s] = fmaf(w, H2,  A[1][s]);
            A[2][s] = fmaf(w, H11, A[2][s]);
            A[3][s] = fmaf(w, H22, A[3][s]);
            A[4][s] = fmaf(w, H12, A[4][s]);
        }
    }
    // ---- emit output row r = t-10 (slot (P+1)%11) ----
    const int es = (P + 1) % 11;
    if (t >= 10 && t <= 73) {                      // wave-uniform branch
        float mu1 = A[0][es], mu2 = A[1][es];
        float x11 = A[2][es], x22 = A[3][es], x12 = A[4][es];
        float mu1s = mu1 * mu1, mu2s = mu2 * mu2, mu12 = mu1 * mu2;
        float v1 = x11 - mu1s, v2 = x22 - mu2s, v12 = x12 - mu12;
        float a1 = fabsf(v1), a2 = fabsf(v2);
        float q12 = sqrtf(a1 * a2);                // sqrt(a1)*sqrt(a2)
        const float C1 = 1e-4f, C2 = 9e-4f, C3 = 4.5e-4f;
        float eL = __fdividef(2.f * mu12 + C1, mu1s + mu2s + C1);
        float eC = __fdividef(2.f * q12 + C2, a1 + a2 + C2);
        float eS = __fdividef(v12 + C3, q12 + C3);
        if (out_ok) { sL += eL; sC += eC; sS += eS; }
    }
    x1 = nx1; x2 = nx2;
}

__global__ __launch_bounds__(256, 4) void ssim_main(
    const float* __restrict__ img1, const float* __restrict__ img2,
    const float* __restrict__ win, float4* __restrict__ part)
{
    const int lane = threadIdx.x & 63;
    const int widx = threadIdx.x >> 6;
    const int wid  = blockIdx.x * WPB + widx;
    const int plane = wid / (NXS * NYS);
    const int rem   = wid % (NXS * NYS);
    const int ys = rem / NXS, xs = rem % NXS;
    const int x0 = xs * XS_W;
    const int y0 = ys * YS_H;
    const int col = x0 - 5 + lane;                 // this lane's image column
    const bool col_ok = (unsigned)col < IMG;
    const bool out_ok = (lane >= 5) && (lane <= 58) && col_ok;

    // separable 1-D Gaussian from diagonal of 2-D window (channel 0):
    // w2d[i][i] = g[i]^2 -> g[i] = sqrt(win[i*12]). Uniform -> SGPRs.
    float g[11];
    #pragma unroll
    for (int j = 0; j < 11; ++j) g[j] = rfl(sqrtf(win[j * 12]));

    // bpermute byte-indices for lane shifts -5..+5 (loop-invariant)
    int si[11];
    #pragma unroll
    for (int j = 0; j < 11; ++j) si[j] = (lane + j - 5) << 2;

    const float* p1 = img1 + (size_t)plane * (IMG * IMG) + col;
    const float* p2 = img2 + (size_t)plane * (IMG * IMG) + col;

    // load row t=0 (gy = y0-5)
    float x1 = 0.f, x2 = 0.f;
    {
        int gy = y0 - 5;
        if (col_ok && (unsigned)gy < IMG) { x1 = p1[gy * IMG]; x2 = p2[gy * IMG]; }
    }

    float A[5][11];
    #pragma unroll
    for (int q = 0; q < 5; ++q)
        #pragma unroll
        for (int s = 0; s < 11; ++s) A[q][s] = 0.f;

    float sL = 0.f, sC = 0.f, sS = 0.f;

    #pragma unroll 1
    for (int T = 0; T < 66; T += 11) {             // t = 0..65
        row_step<0>(T, y0, col_ok, p1, p2, x1, x2, si, g, A, out_ok, sL, sC, sS);
        row_step<1>(T, y0, col_ok, p1, p2, x1, x2, si, g, A, out_ok, sL, sC, sS);
        row_step<2>(T, y0, col_ok, p1, p2, x1, x2, si, g, A, out_ok, sL, sC, sS);
        row_step<3>(T, y0, col_ok, p1, p2, x1, x2, si, g, A, out_ok, sL, sC, sS);
        row_step<4>(T, y0, col_ok, p1, p2, x1, x2, si, g, A, out_ok, sL, sC, sS);
        row_step<5>(T, y0, col_ok, p1, p2, x1, x2, si, g, A, out_ok, sL, sC, sS);
        row_step<6>(T, y0, col_ok, p1, p2, x1, x2, si, g, A, out_ok, sL, sC, sS);
        row_step<7>(T, y0, col_ok, p1, p2, x1, x2, si, g, A, out_ok, sL, sC, sS);
        row_step<8>(T, y0, col_ok, p1, p2, x1, x2, si, g, A, out_ok, sL, sC, sS);
        row_step<9>(T, y0, col_ok, p1, p2, x1, x2, si, g, A, out_ok, sL, sC, sS);
        row_step<10>(T, y0, col_ok, p1, p2, x1, x2, si, g, A, out_ok, sL, sC, sS);
    }
    // tail: t = 66..73
    row_step<0>(66, y0, col_ok, p1, p2, x1, x2, si, g, A, out_ok, sL, sC, sS);
    row_step<1>(66, y0, col_ok, p1, p2, x1, x2, si, g, A, out_ok, sL, sC, sS);
    row_step<2>(66, y0, col_ok, p1, p2, x1, x2, si, g, A, out_ok, sL, sC, sS);
    row_step<3>(66, y0, col_ok, p1, p2, x1, x2, si, g, A, out_ok, sL, sC, sS);
    row_step<4>(66, y0, col_ok, p1, p2, x1, x2, si, g, A, out_ok, sL, sC, sS);
    row_step<5>(66, y0, col_ok, p1, p2, x1, x2, si, g, A, out_ok, sL, sC, sS);
    row_step<6>(66, y0, col_ok, p1, p2, x1, x2, si, g, A, out_ok, sL, sC, sS);
    row_step<7>(66, y0, col_ok, p1, p2, x1, x2, si, g, A, out_ok, sL, sC, sS);

    // ---- wave reduction, then block reduction via tiny LDS, one plain store ----
    #pragma unroll
    for (int off = 32; off > 0; off >>= 1) {
        sL += __shfl_down(sL, off, 64);
        sC += __shfl_down(sC, off, 64);
        sS += __shfl_down(sS, off, 64);
    }
    __shared__ float red[WPB][4];
    if (lane == 0) { red[widx][0] = sL; red[widx][1] = sC; red[widx][2] = sS; }
    __syncthreads();
    if (threadIdx.x == 0) {
        float L = 0.f, C = 0.f, S = 0.f;
        #pragma unroll
        for (int w = 0; w < WPB; ++w) { L += red[w][0]; C += red[w][1]; S += red[w][2]; }
        part[blockIdx.x] = make_float4(L, C, S, 0.f);
    }
}

__global__ void ssim_fin(const float4* __restrict__ part, float* __restrict__ out) {
    const int t = threadIdx.x;
    double L = 0.0, C = 0.0, S = 0.0;
    for (int i = t; i < NBLK; i += 256) {
        float4 p = part[i];
        L += (double)p.x; C += (double)p.y; S += (double)p.z;
    }
    __shared__ double red[256][3];
    red[t][0] = L; red[t][1] = C; red[t][2] = S;
    __syncthreads();
    for (int s = 128; s > 0; s >>= 1) {
        if (t < s) {
            red[t][0] += red[t + s][0];
            red[t][1] += red[t + s][1];
            red[t][2] += red[t + s][2];
        }
        __syncthreads();
    }
    if (t < 3) out[t] = (float)(red[0][t] * INV_NPIX);
}

extern "C" void kernel_launch(void* const* d_in, const int* in_sizes, int n_in,
                              void* d_out, int out_size, void* d_ws, size_t ws_size,
                              hipStream_t stream) {
    const float* img1 = (const float*)d_in[0];
    const float* img2 = (const float*)d_in[1];
    const float* win  = (const float*)d_in[2];
    float* out = (float*)d_out;
    float4* part = (float4*)d_ws;                  // NBLK * 16 B = 30720 B

    ssim_main<<<NBLK, 64 * WPB, 0, stream>>>(img1, img2, win, part);
    ssim_fin<<<1, 256, 0, stream>>>(part, out);
}